// Round 7
// baseline (573.636 us; speedup 1.0000x reference)
//
#include <hip/hip_runtime.h>
#include <hip/hip_fp16.h>
#include <math.h>

#define Bb 8
#define Tt 4
#define Nn 2048
#define Dd 256
#define Mm 4096
#define Ee 8
#define ROWS (Bb*Nn)   // 16384
#define KSEL 8
#define KC 16          // ranking candidates

// output offsets (floats)
#define O_GATE 0LL
#define O_MEMR 131072LL
#define O_LABR 4325376LL
#define O_MLAB 4456448LL
#define O_ATTW 4489216LL

// ws layout (bytes)
#define WS_WT    0LL            // 256 KB fp32 WT
#define WS_KH    262144LL       // 2 MB f16 key
#define WS_QH    2359296LL      // 8 MB f16 q

typedef float f32x4 __attribute__((ext_vector_type(4)));
typedef _Float16 f16x8 __attribute__((ext_vector_type(8)));

__device__ __forceinline__ unsigned short f2h(float x) {
    __half h = __float2half(x);
    return *reinterpret_cast<unsigned short*>(&h);
}

// ---------------- K0: transpose W (256x256) into ws ----------------
__global__ void k_transpose(const float* __restrict__ W, float* __restrict__ WT) {
    int i = blockIdx.x * 256 + threadIdx.x;
    int r = i >> 8, c = i & 255;
    WT[c * 256 + r] = W[r * 256 + c];
}

// ---------------- K1: x = mean_T(prop); q = tanh(x @ W^T + b) -> f32 + f16 ----------------
__global__ __launch_bounds__(256) void k_q(const float* __restrict__ prop,
                                           const float* __restrict__ WT,
                                           const float* __restrict__ bias,
                                           float* __restrict__ qf,
                                           unsigned short* __restrict__ qh) {
    __shared__ float xs[16][256];
    int tid = threadIdx.x;
    int row0 = blockIdx.x * 16;
    #pragma unroll
    for (int r = 0; r < 16; ++r) {
        int row = row0 + r;
        int b = row >> 11;
        int n = row & 2047;
        const float* p = prop + ((long long)(b * Tt) * Nn + n) * Dd + tid;
        float s = 0.f;
        #pragma unroll
        for (int t = 0; t < Tt; ++t) s += p[(long long)t * Nn * Dd];
        xs[r][tid] = s * 0.25f;
    }
    __syncthreads();
    float acc[16];
    #pragma unroll
    for (int r = 0; r < 16; ++r) acc[r] = 0.f;
    int c = tid;
    for (int d = 0; d < 256; ++d) {
        float wv = WT[d * 256 + c];
        #pragma unroll
        for (int r = 0; r < 16; ++r) acc[r] = fmaf(xs[r][d], wv, acc[r]);
    }
    float bv = bias[c];
    #pragma unroll
    for (int r = 0; r < 16; ++r) {
        float qv = tanhf(acc[r] + bv);
        long long o = (long long)(row0 + r) * Dd + c;
        qf[o] = qv;
        qh[o] = f2h(qv);
    }
}

// ---------------- K1b: key -> f16 ----------------
__global__ void k_key16(const float* __restrict__ key, unsigned short* __restrict__ kh) {
    int idx = blockIdx.x * 256 + threadIdx.x;
    kh[idx] = f2h(key[idx]);
}

// ---------------- K2: mem_label = softmax(mem @ w_gate) ----------------
__global__ __launch_bounds__(256) void k_mlabel(const float* __restrict__ mem,
                                                const float* __restrict__ wg,
                                                float* __restrict__ mlab) {
    int m = blockIdx.x * 256 + threadIdx.x;
    if (m >= Mm) return;
    float acc[Ee];
    #pragma unroll
    for (int e = 0; e < Ee; ++e) acc[e] = 0.f;
    const float* mr = mem + (long long)m * Dd;
    for (int d = 0; d < Dd; ++d) {
        float mv = mr[d];
        #pragma unroll
        for (int e = 0; e < Ee; ++e) acc[e] = fmaf(mv, wg[d * Ee + e], acc[e]);
    }
    float mx = acc[0];
    #pragma unroll
    for (int e = 1; e < Ee; ++e) mx = fmaxf(mx, acc[e]);
    float z = 0.f;
    #pragma unroll
    for (int e = 0; e < Ee; ++e) { acc[e] = expf(acc[e] - mx); z += acc[e]; }
    float inv = 1.f / z;
    #pragma unroll
    for (int e = 0; e < Ee; ++e) mlab[(long long)m * Ee + e] = acc[e] * inv;
}

// ---------------- K3: fused GEMM + online top-k + refine + all outputs ----------------
// 256 blocks x 4 waves; wave owns 16 rows, sweeps all 4096 cols. No att matrix.
__global__ __launch_bounds__(256) void k_rank(const unsigned short* __restrict__ qh,
                                              const unsigned short* __restrict__ kh,
                                              const float* __restrict__ qf,
                                              const float* __restrict__ key,
                                              const float* __restrict__ mem,
                                              const float* __restrict__ mlab,
                                              float* __restrict__ gate,
                                              float* __restrict__ memr,
                                              float* __restrict__ labr,
                                              float* __restrict__ attw) {
    __shared__ float lds_p[4][16][16];
    __shared__ int   lds_i[4][16][16];
    int tid = threadIdx.x;
    int lane = tid & 63, w = tid >> 6;
    int lr = lane & 15, j = lane >> 4;
    long long row0 = (long long)blockIdx.x * 64 + w * 16;

    // ---- Phase A: A-fragments for 16 rows (registers) ----
    f16x8 af[8];
    #pragma unroll
    for (int k0 = 0; k0 < 8; ++k0)
        af[k0] = *(const f16x8*)(qh + (row0 + lr) * 256 + k0 * 32 + j * 8);

    // ---- Phase B: sweep 256 col-tiles; online per-lane top-8 packed keys ----
    unsigned int L[4][8];
    float thr[4];
    #pragma unroll
    for (int r = 0; r < 4; ++r) {
        thr[r] = -INFINITY;
        #pragma unroll
        for (int s = 0; s < 8; ++s) L[r][s] = 0u;
    }

    f16x8 bbA[8], bbB[8];
    #pragma unroll
    for (int k0 = 0; k0 < 8; ++k0)
        bbA[k0] = *(const f16x8*)(kh + (long long)lr * 256 + k0 * 32 + j * 8);

    auto process = [&](const f16x8* bb, int t) {
        f32x4 acc = (f32x4){0.f, 0.f, 0.f, 0.f};
        #pragma unroll
        for (int k0 = 0; k0 < 8; ++k0)
            acc = __builtin_amdgcn_mfma_f32_16x16x32_f16(af[k0], bb[k0], acc, 0, 0, 0);
        unsigned int colkey = (unsigned)(4095 - (t * 16 + lr));
        #pragma unroll
        for (int r = 0; r < 4; ++r) {
            float x = acc[r];
            if (x > thr[r]) {
                unsigned int fb = __float_as_uint(x);
                unsigned int mono = fb ^ ((unsigned)((int)fb >> 31) | 0x80000000u);
                unsigned int xx = (mono & 0xFFFFF000u) | colkey;
                #pragma unroll
                for (int s = 0; s < 8; ++s) {
                    unsigned int hi = L[r][s] > xx ? L[r][s] : xx;
                    unsigned int lo = L[r][s] > xx ? xx : L[r][s];
                    L[r][s] = hi; xx = lo;
                }
                unsigned int h20 = L[r][7] & 0xFFFFF000u;
                float nt = (h20 >= 0x80000000u) ? __uint_as_float(h20 ^ 0x80000000u)
                                                : __uint_as_float(~h20);
                thr[r] = (h20 == 0u) ? -INFINITY : nt;
            }
        }
    };

    for (int t2 = 0; t2 < 256; t2 += 2) {
        #pragma unroll
        for (int k0 = 0; k0 < 8; ++k0)
            bbB[k0] = *(const f16x8*)(kh + (long long)((t2 + 1) * 16 + lr) * 256 + k0 * 32 + j * 8);
        process(bbA, t2);
        if (t2 + 2 < 256) {
            #pragma unroll
            for (int k0 = 0; k0 < 8; ++k0)
                bbA[k0] = *(const f16x8*)(kh + (long long)((t2 + 2) * 16 + lr) * 256 + k0 * 32 + j * 8);
        }
        process(bbB, t2 + 1);
        if ((t2 & 15) == 14) __builtin_amdgcn_s_barrier();   // lockstep for L1 B-reuse
    }

    // ---- Phase D: per reg (4 rows across the 4 groups), pops -> refine -> outputs ----
    #pragma unroll
    for (int r = 0; r < 4; ++r) {
        // 16 pops within each 16-lane group (group j owns rows j*4+r)
        unsigned int ck[KC];
        #pragma unroll
        for (int k = 0; k < KC; ++k) {
            unsigned int bv = L[r][0];
            #pragma unroll
            for (int d = 1; d < 16; d <<= 1) {
                unsigned int ov = (unsigned)__shfl_xor((int)bv, d);
                bv = bv > ov ? bv : ov;
            }
            ck[k] = bv;
            bool won = (L[r][0] == bv);
            #pragma unroll
            for (int s = 0; s < 7; ++s) L[r][s] = won ? L[r][s + 1] : L[r][s];
            L[r][7] = won ? 0u : L[r][7];
        }

        for (int jj = 0; jj < 4; ++jj) {
            long long row = row0 + jj * 4 + r;
            int rloc = jj * 4 + r;

            int civ[KC];
            #pragma unroll
            for (int s = 0; s < KC; ++s) {
                unsigned int cks = (unsigned)__shfl((int)ck[s], jj * 16);
                civ[s] = 4095 - (int)(cks & 0xFFFu);
            }

            // refine: cand c = lr, slice g = j (64 elems), fp64 with 4 chains
            int cidx = civ[0];
            #pragma unroll
            for (int s = 1; s < KC; ++s) cidx = (lr == s) ? civ[s] : cidx;
            const float* qrow = qf + row * Dd;
            const float* krow = key + (long long)cidx * Dd;
            double d0 = 0.0, d1 = 0.0, d2 = 0.0, d3 = 0.0;
            #pragma unroll
            for (int i = 0; i < 16; ++i) {
                float4 qv = *(const float4*)(qrow + j * 64 + i * 4);
                float4 kv = *(const float4*)(krow + j * 64 + i * 4);
                d0 = fma((double)qv.x, (double)kv.x, d0);
                d1 = fma((double)qv.y, (double)kv.y, d1);
                d2 = fma((double)qv.z, (double)kv.z, d2);
                d3 = fma((double)qv.w, (double)kv.w, d3);
            }
            double dacc = (d0 + d1) + (d2 + d3);
            dacc += __shfl_xor(dacc, 16);
            dacc += __shfl_xor(dacc, 32);
            float rvf = (float)dacc;
            float cv[KC];
            #pragma unroll
            for (int s = 0; s < KC; ++s) cv[s] = __shfl(rvf, s);

            // all-pairs rank (value desc, idx asc); selected = rank < 8
            unsigned int m32[KC];
            #pragma unroll
            for (int s = 0; s < KC; ++s) {
                unsigned int fb = __float_as_uint(cv[s]);
                m32[s] = fb ^ ((unsigned)((int)fb >> 31) | 0x80000000u);
            }
            bool sel[KC];
            #pragma unroll
            for (int s = 0; s < KC; ++s) {
                int rk = 0;
                #pragma unroll
                for (int t = 0; t < KC; ++t) {
                    if (t != s) {
                        bool gt = (m32[t] > m32[s]) || (m32[t] == m32[s] && civ[t] < civ[s]);
                        rk += gt ? 1 : 0;
                    }
                }
                sel[s] = (rk < KSEL);
            }

            float mx = cv[0];
            #pragma unroll
            for (int s = 1; s < KC; ++s) mx = fmaxf(mx, cv[s]);
            float p[KC]; float z = 0.f;
            #pragma unroll
            for (int s = 0; s < KC; ++s) { p[s] = sel[s] ? expf(cv[s] - mx) : 0.f; z += p[s]; }
            float inv = 1.f / z;
            #pragma unroll
            for (int s = 0; s < KC; ++s) p[s] *= inv;

            // mem_retrieved (qf row already fully consumed by refine above)
            {
                float4 a = make_float4(0.f, 0.f, 0.f, 0.f);
                #pragma unroll
                for (int s = 0; s < KC; ++s) {
                    if (sel[s]) {
                        const float4 mv = *(const float4*)(mem + (long long)civ[s] * Dd + lane * 4);
                        a.x = fmaf(p[s], mv.x, a.x); a.y = fmaf(p[s], mv.y, a.y);
                        a.z = fmaf(p[s], mv.z, a.z); a.w = fmaf(p[s], mv.w, a.w);
                    }
                }
                *(float4*)(memr + row * Dd + lane * 4) = a;
            }
            if (lane < Ee) {
                float s8 = 0.f;
                #pragma unroll
                for (int s = 0; s < KC; ++s)
                    if (sel[s]) s8 = fmaf(p[s], mlab[(long long)civ[s] * Ee + lane], s8);
                gate[row * Ee + lane] = s8;
                labr[row * Ee + lane] = s8;
            }
            // stash scatter pairs; zero the attw row (NT, drained at the barrier below)
            if (lane < KC) {
                float myp = p[0]; int myi = civ[0];
                #pragma unroll
                for (int s = 1; s < KC; ++s) {
                    myp = (lane == s) ? p[s] : myp;
                    myi = (lane == s) ? civ[s] : myi;
                }
                lds_p[w][rloc][lane] = myp;
                lds_i[w][rloc][lane] = myi;
            }
            float* awrow = attw + row * Mm;
            f32x4 zz = (f32x4){0.f, 0.f, 0.f, 0.f};
            #pragma unroll
            for (int tt = 0; tt < 16; ++tt)
                __builtin_nontemporal_store(zz, (f32x4*)(awrow + (tt * 64 + lane) * 4));
        }
    }

    __syncthreads();   // drains vmcnt(0): all zero-stores complete; LDS visible

    // ---- D2: sparse scatter (4 entries/lane over this wave's 16 rows x 16 slots) ----
    #pragma unroll
    for (int i = 0; i < 4; ++i) {
        int e = lane * 4 + i;
        int rl = e >> 4, sl = e & 15;
        float pv = lds_p[w][rl][sl];
        int iv = lds_i[w][rl][sl];
        attw[(row0 + rl) * Mm + iv] = pv;
    }
}

extern "C" void kernel_launch(void* const* d_in, const int* in_sizes, int n_in,
                              void* d_out, int out_size, void* d_ws, size_t ws_size,
                              hipStream_t stream) {
    const float* prop = (const float*)d_in[0];
    const float* W    = (const float*)d_in[2];
    const float* bias = (const float*)d_in[3];
    const float* key  = (const float*)d_in[4];
    const float* mem  = (const float*)d_in[5];
    const float* wg   = (const float*)d_in[6];

    float* out  = (float*)d_out;
    float* gate = out + O_GATE;
    float* memr = out + O_MEMR;
    float* labr = out + O_LABR;
    float* mlab = out + O_MLAB;
    float* attw = out + O_ATTW;

    char* ws = (char*)d_ws;
    float*          WT = (float*)(ws + WS_WT);
    unsigned short* kh = (unsigned short*)(ws + WS_KH);
    unsigned short* qh = (unsigned short*)(ws + WS_QH);
    float*          qf = memr;   // fp32 q in memr output region (dead before overwrite)

    k_transpose<<<256, 256, 0, stream>>>(W, WT);
    k_q<<<ROWS / 16, 256, 0, stream>>>(prop, WT, bias, qf, qh);
    k_key16<<<(Mm * Dd) / 256, 256, 0, stream>>>(key, kh);
    k_mlabel<<<Mm / 256, 256, 0, stream>>>(mem, wg, mlab);
    k_rank<<<ROWS / 64, 256, 0, stream>>>(qh, kh, qf, key, mem, mlab, gate, memr, labr, attw);
}

// Round 9
// 274.092 us; speedup vs baseline: 2.0929x; 2.0929x over previous
//
#include <hip/hip_runtime.h>
#include <hip/hip_fp16.h>
#include <math.h>

#define Bb 8
#define Tt 4
#define Nn 2048
#define Dd 256
#define Mm 4096
#define Ee 8
#define ROWS (Bb*Nn)   // 16384
#define KSEL 8
#define KC 16          // ranking candidates

// output offsets (floats)
#define O_GATE 0LL
#define O_MEMR 131072LL
#define O_LABR 4325376LL
#define O_MLAB 4456448LL
#define O_ATTW 4489216LL

// ws layout (bytes) — ~159 MB used; ws ≈1.1 GB (0xAA fill = 1.146 GB)
#define WS_WT    0LL            // 256 KB fp32 WT
#define WS_KH    262144LL       // 2 MB f16 key
#define WS_ATTH  16777216LL     // 128 MB f16 att (16384 x 4096)
#define WS_QH    150994944LL    // 8 MB f16 q

typedef float f32x4 __attribute__((ext_vector_type(4)));
typedef short short8 __attribute__((ext_vector_type(8)));
typedef _Float16 f16x8 __attribute__((ext_vector_type(8)));

__device__ __forceinline__ unsigned short f2h(float x) {
    __half h = __float2half(x);
    return *reinterpret_cast<unsigned short*>(&h);
}

__device__ __forceinline__ void gload_lds16(const void* g, void* l) {
    __builtin_amdgcn_global_load_lds(
        (const __attribute__((address_space(1))) unsigned int*)g,
        (__attribute__((address_space(3))) unsigned int*)l,
        16, 0, 0);
}

// ---------------- K0: prep (transpose W | key->f16 | mem_label) ----------------
// grid = 256 + 4096 + 16 = 4368 blocks
__global__ __launch_bounds__(256) void k_prep(const float* __restrict__ W, float* __restrict__ WT,
                                              const float* __restrict__ key, unsigned short* __restrict__ kh,
                                              const float* __restrict__ mem, const float* __restrict__ wg,
                                              float* __restrict__ mlab) {
    int b = blockIdx.x, tid = threadIdx.x;
    if (b < 256) {
        int i = b * 256 + tid;
        int r = i >> 8, c = i & 255;
        WT[c * 256 + r] = W[r * 256 + c];
    } else if (b < 256 + 4096) {
        int idx = (b - 256) * 256 + tid;     // covers all Mm*Dd = 1048576
        kh[idx] = f2h(key[idx]);
    } else {
        int m = (b - 4352) * 256 + tid;
        if (m < Mm) {
            float acc[Ee];
            #pragma unroll
            for (int e = 0; e < Ee; ++e) acc[e] = 0.f;
            const float* mr = mem + (long long)m * Dd;
            for (int d = 0; d < Dd; ++d) {
                float mv = mr[d];
                #pragma unroll
                for (int e = 0; e < Ee; ++e) acc[e] = fmaf(mv, wg[d * Ee + e], acc[e]);
            }
            float mx = acc[0];
            #pragma unroll
            for (int e = 1; e < Ee; ++e) mx = fmaxf(mx, acc[e]);
            float z = 0.f;
            #pragma unroll
            for (int e = 0; e < Ee; ++e) { acc[e] = expf(acc[e] - mx); z += acc[e]; }
            float inv = 1.f / z;
            #pragma unroll
            for (int e = 0; e < Ee; ++e) mlab[(long long)m * Ee + e] = acc[e] * inv;
        }
    }
}

// ---------------- K1: x = mean_T(prop); q = tanh(x @ W^T + b) -> f32 + f16 ----------------
__global__ __launch_bounds__(256) void k_q(const float* __restrict__ prop,
                                           const float* __restrict__ WT,
                                           const float* __restrict__ bias,
                                           float* __restrict__ qf,
                                           unsigned short* __restrict__ qh) {
    __shared__ float xs[16][256];
    int tid = threadIdx.x;
    int row0 = blockIdx.x * 16;
    #pragma unroll
    for (int r = 0; r < 16; ++r) {
        int row = row0 + r;
        int b = row >> 11;
        int n = row & 2047;
        const float* p = prop + ((long long)(b * Tt) * Nn + n) * Dd + tid;
        float s = 0.f;
        #pragma unroll
        for (int t = 0; t < Tt; ++t) s += p[(long long)t * Nn * Dd];
        xs[r][tid] = s * 0.25f;
    }
    __syncthreads();
    float acc[16];
    #pragma unroll
    for (int r = 0; r < 16; ++r) acc[r] = 0.f;
    int c = tid;
    for (int d = 0; d < 256; ++d) {
        float wv = WT[d * 256 + c];
        #pragma unroll
        for (int r = 0; r < 16; ++r) acc[r] = fmaf(xs[r][d], wv, acc[r]);
    }
    float bv = bias[c];
    #pragma unroll
    for (int r = 0; r < 16; ++r) {
        float qv = tanhf(acc[r] + bv);
        long long o = (long long)(row0 + r) * Dd + c;
        qf[o] = qv;
        qh[o] = f2h(qv);
    }
}

// ---------------- K3: att_f16 = q @ key^T, fp16 MFMA; LDS-staged coalesced C-store ----------------
// 1D grid of 4096 blocks, bijective XCD swizzle (4096 % 8 == 0)
__global__ __launch_bounds__(256) void k_att(const unsigned short* __restrict__ qh,
                                             const unsigned short* __restrict__ kh,
                                             unsigned short* __restrict__ attH) {
    // staging uses [0, 8192); C-tile reuses full array: 128 rows x stride 136 shorts (34 KB)
    __shared__ __align__(16) unsigned short smem[17408];
    int bid = blockIdx.x;
    int swz = (bid & 7) * 512 + (bid >> 3);     // XCD-contiguous chunks
    int bx = swz & 31;                          // col tile 0..31
    int by = swz >> 5;                          // row tile 0..127
    int tid = threadIdx.x;
    int lane = tid & 63, w = tid >> 6;
    int wr = w >> 1, wc = w & 1;
    long long row0 = (long long)by * 128;
    long long col0 = (long long)bx * 128;

    f32x4 acc[4][4];
    #pragma unroll
    for (int m = 0; m < 4; ++m)
        #pragma unroll
        for (int n = 0; n < 4; ++n) acc[m][n] = (f32x4){0.f, 0.f, 0.f, 0.f};

    int rr = lane >> 2;
    int sp = lane & 3;

    auto stage = [&](int k0) {
        #pragma unroll
        for (int t = 0; t < 2; ++t) {
            const unsigned short* src = t ? kh : qh;
            long long b0 = t ? col0 : row0;
            #pragma unroll
            for (int i = 0; i < 2; ++i) {
                int r = w * 32 + i * 16 + rr;
                int sl = sp ^ ((r >> 1) & 3);
                const unsigned short* g = src + (b0 + r) * 256 + k0 * 32 + sl * 8;
                unsigned short* l = smem + t * 4096 + (w * 32 + i * 16) * 32;
                gload_lds16(g, l);
            }
        }
    };

    stage(0);
    for (int k0 = 0; k0 < 8; ++k0) {
        __syncthreads();
        int lr = lane & 15, j = lane >> 4;
        f16x8 ah[4], bh[4];
        #pragma unroll
        for (int m = 0; m < 4; ++m) {
            int r = wr * 64 + m * 16 + lr;
            int off = r * 32 + ((j ^ ((r >> 1) & 3)) * 8);
            ah[m] = *(const f16x8*)(smem + off);
        }
        #pragma unroll
        for (int n = 0; n < 4; ++n) {
            int r = wc * 64 + n * 16 + lr;
            int off = r * 32 + ((j ^ ((r >> 1) & 3)) * 8);
            bh[n] = *(const f16x8*)(smem + 4096 + off);
        }
        #pragma unroll
        for (int m = 0; m < 4; ++m)
            #pragma unroll
            for (int n = 0; n < 4; ++n)
                acc[m][n] = __builtin_amdgcn_mfma_f32_16x16x32_f16(ah[m], bh[n], acc[m][n], 0, 0, 0);
        if (k0 < 7) { __syncthreads(); stage(k0 + 1); }
    }

    // ---- C epilogue: fragments -> LDS (f16, stride 136) -> coalesced short8 stores ----
    __syncthreads();   // all waves done reading staging LDS
    {
        int lr = lane & 15, j = lane >> 4;
        #pragma unroll
        for (int m = 0; m < 4; ++m)
            #pragma unroll
            for (int n = 0; n < 4; ++n) {
                int c = wc * 64 + n * 16 + lr;
                #pragma unroll
                for (int reg = 0; reg < 4; ++reg) {
                    int r = wr * 64 + m * 16 + j * 4 + reg;
                    smem[r * 136 + c] = f2h(acc[m][n][reg]);
                }
            }
    }
    __syncthreads();
    {
        int tr = tid >> 4;      // 0..15
        int tc = tid & 15;      // 0..15
        #pragma unroll
        for (int pass = 0; pass < 8; ++pass) {
            int r = pass * 16 + tr;
            short8 vv = *(const short8*)(smem + r * 136 + tc * 8);
            *(short8*)(attH + (row0 + r) * Mm + col0 + tc * 8) = vv;
        }
    }
}

// ---------------- K4: top-16 rank -> fp64 refine -> top-8 + ALL outputs (attw fused) ----------------
__global__ __launch_bounds__(256) void k_final2(const unsigned short* __restrict__ attH,
                                                const float* __restrict__ qf,
                                                const float* __restrict__ key,
                                                const float* __restrict__ mem,
                                                const float* __restrict__ mlab,
                                                float* __restrict__ gate,
                                                float* __restrict__ memr,
                                                float* __restrict__ labr,
                                                float* __restrict__ attw) {
    int tid = threadIdx.x;
    int lane = tid & 63;
    long long row = (long long)blockIdx.x * 4 + (tid >> 6);
    const unsigned short* arow = attH + row * Mm;

    // ---- per-lane top-8 packed keys: key = mono16(f16)<<16 | (4095-idx) ----
    unsigned int v[8];
    #pragma unroll
    for (int s = 0; s < 8; ++s) v[s] = 0u;

    #pragma unroll
    for (int t = 0; t < 8; ++t) {
        int c8 = t * 64 + lane;
        short8 x8 = *(const short8*)(arow + c8 * 8);
        unsigned int rb = (unsigned)(4095 - c8 * 8);
        #pragma unroll
        for (int jj = 0; jj < 8; ++jj) {
            unsigned int b = (unsigned short)x8[jj];
            unsigned int sr = (unsigned)((int)(b << 16) >> 31);    // 0 or all-ones
            unsigned int mono = b ^ ((sr >> 17) | 0x8000u);        // order-preserving
            unsigned int keyv = (mono << 16) | (rb - jj);
            if (keyv > v[7]) {
                unsigned int x = keyv;
                #pragma unroll
                for (int s = 0; s < 8; ++s) {
                    unsigned int hi = v[s] > x ? v[s] : x;
                    unsigned int lo = v[s] > x ? x : v[s];
                    v[s] = hi; x = lo;
                }
            }
        }
    }

    // ---- extract global top-16 via wave-max pops ----
    unsigned int sk[KC];
    #pragma unroll
    for (int k = 0; k < KC; ++k) {
        unsigned int bv = v[0];
        #pragma unroll
        for (int d = 1; d < 64; d <<= 1) {
            unsigned int ov = (unsigned)__shfl_xor((int)bv, d);
            bv = bv > ov ? bv : ov;
        }
        sk[k] = bv;
        bool won = (v[0] == bv);
        #pragma unroll
        for (int s = 0; s < 7; ++s) v[s] = won ? v[s + 1] : v[s];
        v[7] = won ? 0u : v[7];
    }

    int civ[KC];
    #pragma unroll
    for (int s = 0; s < KC; ++s) civ[s] = 4095 - (int)(sk[s] & 0xFFFFu);

    // ---- refine: candidate c = lane&15, slice g = lane>>4, fp64 dot ----
    int c = lane & 15, g = lane >> 4;
    int cidx = civ[0];
    #pragma unroll
    for (int s = 1; s < KC; ++s) cidx = (c == s) ? civ[s] : cidx;
    const float* qrow = qf + row * Dd;
    const float* krow = key + (long long)cidx * Dd;
    double dacc = 0.0;
    #pragma unroll
    for (int i = 0; i < 16; ++i) {
        float4 qv = *(const float4*)(qrow + g * 64 + i * 4);
        float4 kv = *(const float4*)(krow + g * 64 + i * 4);
        dacc = fma((double)qv.x, (double)kv.x, dacc);
        dacc = fma((double)qv.y, (double)kv.y, dacc);
        dacc = fma((double)qv.z, (double)kv.z, dacc);
        dacc = fma((double)qv.w, (double)kv.w, dacc);
    }
    dacc += __shfl_xor(dacc, 16);
    dacc += __shfl_xor(dacc, 32);
    float rvf = (float)dacc;

    float cv[KC];
    #pragma unroll
    for (int s = 0; s < KC; ++s) cv[s] = __shfl(rvf, s);

    // ---- all-pairs rank on (refined value desc, idx asc); selected = rank<8 ----
    unsigned int m32[KC];
    #pragma unroll
    for (int s = 0; s < KC; ++s) {
        unsigned int fb = __float_as_uint(cv[s]);
        m32[s] = fb ^ ((unsigned)((int)fb >> 31) | 0x80000000u);
    }
    bool sel[KC];
    #pragma unroll
    for (int s = 0; s < KC; ++s) {
        int r = 0;
        #pragma unroll
        for (int t = 0; t < KC; ++t) {
            if (t != s) {
                bool gt = (m32[t] > m32[s]) || (m32[t] == m32[s] && civ[t] < civ[s]);
                r += gt ? 1 : 0;
            }
        }
        sel[s] = (r < KSEL);
    }

    // ---- softmax over selected ----
    float mx = cv[0];
    #pragma unroll
    for (int s = 1; s < KC; ++s) mx = fmaxf(mx, cv[s]);
    float p[KC]; float z = 0.f;
    #pragma unroll
    for (int s = 0; s < KC; ++s) { p[s] = sel[s] ? expf(cv[s] - mx) : 0.f; z += p[s]; }
    float inv = 1.f / z;
    #pragma unroll
    for (int s = 0; s < KC; ++s) p[s] *= inv;

    // ---- mem_retrieved (reads mem rows; overwrites q row after full read) ----
    {
        float4 a = make_float4(0.f, 0.f, 0.f, 0.f);
        #pragma unroll
        for (int s = 0; s < KC; ++s) {
            if (sel[s]) {
                const float4 mv = *(const float4*)(mem + (long long)civ[s] * Dd + lane * 4);
                a.x = fmaf(p[s], mv.x, a.x); a.y = fmaf(p[s], mv.y, a.y);
                a.z = fmaf(p[s], mv.z, a.z); a.w = fmaf(p[s], mv.w, a.w);
            }
        }
        *(float4*)(memr + row * Dd + lane * 4) = a;
    }

    if (lane < Ee) {
        float s8 = 0.f;
        #pragma unroll
        for (int s = 0; s < KC; ++s)
            if (sel[s]) s8 = fmaf(p[s], mlab[(long long)civ[s] * Ee + lane], s8);
        gate[row * Ee + lane] = s8;
        labr[row * Ee + lane] = s8;
    }

    // ---- att_w row: NT zero-fill, barrier (drains stores), sparse insert ----
    float* awrow = attw + row * Mm;
    {
        f32x4 zz = (f32x4){0.f, 0.f, 0.f, 0.f};
        #pragma unroll
        for (int t = 0; t < 16; ++t)
            __builtin_nontemporal_store(zz, (f32x4*)(awrow + (t * 64 + lane) * 4));
    }
    __syncthreads();   // s_waitcnt vmcnt(0) + barrier: zero-stores ordered before inserts
    if (lane < KC) {
        float myp = p[0]; int myi = civ[0];
        #pragma unroll
        for (int s = 1; s < KC; ++s) {
            myp = (lane == s) ? p[s] : myp;
            myi = (lane == s) ? civ[s] : myi;
        }
        awrow[myi] = myp;   // unselected lanes write 0.0 at their own idx (true value is 0.0)
    }
}

extern "C" void kernel_launch(void* const* d_in, const int* in_sizes, int n_in,
                              void* d_out, int out_size, void* d_ws, size_t ws_size,
                              hipStream_t stream) {
    const float* prop = (const float*)d_in[0];
    const float* W    = (const float*)d_in[2];
    const float* bias = (const float*)d_in[3];
    const float* key  = (const float*)d_in[4];
    const float* mem  = (const float*)d_in[5];
    const float* wg   = (const float*)d_in[6];

    float* out  = (float*)d_out;
    float* gate = out + O_GATE;
    float* memr = out + O_MEMR;
    float* labr = out + O_LABR;
    float* mlab = out + O_MLAB;
    float* attw = out + O_ATTW;

    char* ws = (char*)d_ws;
    float*          WT   = (float*)(ws + WS_WT);
    unsigned short* kh   = (unsigned short*)(ws + WS_KH);
    unsigned short* attH = (unsigned short*)(ws + WS_ATTH);
    unsigned short* qh   = (unsigned short*)(ws + WS_QH);
    float*          qf   = memr;   // fp32 q in memr output region (dead before overwrite)

    k_prep<<<4368, 256, 0, stream>>>(W, WT, key, kh, mem, wg, mlab);
    k_q<<<ROWS / 16, 256, 0, stream>>>(prop, WT, bias, qf, qh);
    k_att<<<4096, 256, 0, stream>>>(qh, kh, attH);
    k_final2<<<ROWS / 4, 256, 0, stream>>>(attH, qf, key, mem, mlab, gate, memr, labr, attw);
}

// Round 10
// 263.590 us; speedup vs baseline: 2.1762x; 1.0398x over previous
//
#include <hip/hip_runtime.h>
#include <hip/hip_fp16.h>
#include <math.h>

#define Bb 8
#define Tt 4
#define Nn 2048
#define Dd 256
#define Mm 4096
#define Ee 8
#define ROWS (Bb*Nn)   // 16384
#define KSEL 8
#define KC 16          // ranking candidates

// output offsets (floats)
#define O_GATE 0LL
#define O_MEMR 131072LL
#define O_LABR 4325376LL
#define O_MLAB 4456448LL
#define O_ATTW 4489216LL

// ws layout (bytes)
#define WS_WT    0LL            // 256 KB fp32 WT
#define WS_KH    262144LL       // 2 MB f16 key
#define WS_CAND  16777216LL     // 16.8 MB u32 cand[32][16384][8]
#define WS_QH    150994944LL    // 8 MB f16 q

typedef float f32x4 __attribute__((ext_vector_type(4)));
typedef short short8 __attribute__((ext_vector_type(8)));
typedef _Float16 f16x8 __attribute__((ext_vector_type(8)));

__device__ __forceinline__ unsigned short f2h(float x) {
    __half h = __float2half(x);
    return *reinterpret_cast<unsigned short*>(&h);
}

__device__ __forceinline__ void gload_lds16(const void* g, void* l) {
    __builtin_amdgcn_global_load_lds(
        (const __attribute__((address_space(1))) unsigned int*)g,
        (__attribute__((address_space(3))) unsigned int*)l,
        16, 0, 0);
}

// ---------------- K0: prep (transpose W | key->f16 | mem_label) ----------------
// grid = 256 + 4096 + 16 = 4368 blocks
__global__ __launch_bounds__(256) void k_prep(const float* __restrict__ W, float* __restrict__ WT,
                                              const float* __restrict__ key, unsigned short* __restrict__ kh,
                                              const float* __restrict__ mem, const float* __restrict__ wg,
                                              float* __restrict__ mlab) {
    int b = blockIdx.x, tid = threadIdx.x;
    if (b < 256) {
        int i = b * 256 + tid;
        int r = i >> 8, c = i & 255;
        WT[c * 256 + r] = W[r * 256 + c];
    } else if (b < 256 + 4096) {
        int idx = (b - 256) * 256 + tid;     // covers all Mm*Dd = 1048576
        kh[idx] = f2h(key[idx]);
    } else {
        int m = (b - 4352) * 256 + tid;
        if (m < Mm) {
            float acc[Ee];
            #pragma unroll
            for (int e = 0; e < Ee; ++e) acc[e] = 0.f;
            const float* mr = mem + (long long)m * Dd;
            for (int d = 0; d < Dd; ++d) {
                float mv = mr[d];
                #pragma unroll
                for (int e = 0; e < Ee; ++e) acc[e] = fmaf(mv, wg[d * Ee + e], acc[e]);
            }
            float mx = acc[0];
            #pragma unroll
            for (int e = 1; e < Ee; ++e) mx = fmaxf(mx, acc[e]);
            float z = 0.f;
            #pragma unroll
            for (int e = 0; e < Ee; ++e) { acc[e] = expf(acc[e] - mx); z += acc[e]; }
            float inv = 1.f / z;
            #pragma unroll
            for (int e = 0; e < Ee; ++e) mlab[(long long)m * Ee + e] = acc[e] * inv;
        }
    }
}

// ---------------- K1: x = mean_T(prop); q = tanh(x @ W^T + b) -> f32 + f16 ----------------
__global__ __launch_bounds__(256) void k_q(const float* __restrict__ prop,
                                           const float* __restrict__ WT,
                                           const float* __restrict__ bias,
                                           float* __restrict__ qf,
                                           unsigned short* __restrict__ qh) {
    __shared__ float xs[16][256];
    int tid = threadIdx.x;
    int row0 = blockIdx.x * 16;
    #pragma unroll
    for (int r = 0; r < 16; ++r) {
        int row = row0 + r;
        int b = row >> 11;
        int n = row & 2047;
        const float* p = prop + ((long long)(b * Tt) * Nn + n) * Dd + tid;
        float s = 0.f;
        #pragma unroll
        for (int t = 0; t < Tt; ++t) s += p[(long long)t * Nn * Dd];
        xs[r][tid] = s * 0.25f;
    }
    __syncthreads();
    float acc[16];
    #pragma unroll
    for (int r = 0; r < 16; ++r) acc[r] = 0.f;
    int c = tid;
    for (int d = 0; d < 256; ++d) {
        float wv = WT[d * 256 + c];
        #pragma unroll
        for (int r = 0; r < 16; ++r) acc[r] = fmaf(xs[r][d], wv, acc[r]);
    }
    float bv = bias[c];
    #pragma unroll
    for (int r = 0; r < 16; ++r) {
        float qv = tanhf(acc[r] + bv);
        long long o = (long long)(row0 + r) * Dd + c;
        qf[o] = qv;
        qh[o] = f2h(qv);
    }
}

// ---------------- K3: att tile = q @ key^T (fp16 MFMA) + per-tile top-8/row -> cand keys ----------------
// 1D grid of 4096 blocks, bijective XCD swizzle (4096 % 8 == 0). No att matrix materialized.
__global__ __launch_bounds__(256) void k_att(const unsigned short* __restrict__ qh,
                                             const unsigned short* __restrict__ kh,
                                             unsigned int* __restrict__ cand) {
    // staging uses [0, 8192); C-tile: 128 rows x stride 136 shorts, slot-XOR swizzled
    __shared__ __align__(16) unsigned short smem[17408];
    int bid = blockIdx.x;
    int swz = (bid & 7) * 512 + (bid >> 3);     // XCD-contiguous chunks
    int bx = swz & 31;                          // col tile 0..31
    int by = swz >> 5;                          // row tile 0..127
    int tid = threadIdx.x;
    int lane = tid & 63, w = tid >> 6;
    int wr = w >> 1, wc = w & 1;
    long long row0 = (long long)by * 128;
    long long col0 = (long long)bx * 128;

    f32x4 acc[4][4];
    #pragma unroll
    for (int m = 0; m < 4; ++m)
        #pragma unroll
        for (int n = 0; n < 4; ++n) acc[m][n] = (f32x4){0.f, 0.f, 0.f, 0.f};

    int rr = lane >> 2;
    int sp = lane & 3;

    auto stage = [&](int k0) {
        #pragma unroll
        for (int t = 0; t < 2; ++t) {
            const unsigned short* src = t ? kh : qh;
            long long b0 = t ? col0 : row0;
            #pragma unroll
            for (int i = 0; i < 2; ++i) {
                int r = w * 32 + i * 16 + rr;
                int sl = sp ^ ((r >> 1) & 3);
                const unsigned short* g = src + (b0 + r) * 256 + k0 * 32 + sl * 8;
                unsigned short* l = smem + t * 4096 + (w * 32 + i * 16) * 32;
                gload_lds16(g, l);
            }
        }
    };

    stage(0);
    for (int k0 = 0; k0 < 8; ++k0) {
        __syncthreads();
        int lr = lane & 15, j = lane >> 4;
        f16x8 ah[4], bh[4];
        #pragma unroll
        for (int m = 0; m < 4; ++m) {
            int r = wr * 64 + m * 16 + lr;
            int off = r * 32 + ((j ^ ((r >> 1) & 3)) * 8);
            ah[m] = *(const f16x8*)(smem + off);
        }
        #pragma unroll
        for (int n = 0; n < 4; ++n) {
            int r = wc * 64 + n * 16 + lr;
            int off = r * 32 + ((j ^ ((r >> 1) & 3)) * 8);
            bh[n] = *(const f16x8*)(smem + 4096 + off);
        }
        #pragma unroll
        for (int m = 0; m < 4; ++m)
            #pragma unroll
            for (int n = 0; n < 4; ++n)
                acc[m][n] = __builtin_amdgcn_mfma_f32_16x16x32_f16(ah[m], bh[n], acc[m][n], 0, 0, 0);
        if (k0 < 7) { __syncthreads(); stage(k0 + 1); }
    }

    // ---- C fragments -> LDS f16 (stride 136, slot-XOR swizzle on 8-short slots) ----
    __syncthreads();   // all waves done reading staging LDS
    {
        int lr = lane & 15, j = lane >> 4;
        #pragma unroll
        for (int m = 0; m < 4; ++m)
            #pragma unroll
            for (int n = 0; n < 4; ++n) {
                int c = wc * 64 + n * 16 + lr;
                #pragma unroll
                for (int reg = 0; reg < 4; ++reg) {
                    int r = wr * 64 + m * 16 + j * 4 + reg;
                    int pc = (((c >> 3) ^ (r & 7)) << 3) | (c & 7);
                    smem[r * 136 + pc] = f2h(acc[m][n][reg]);
                }
            }
    }
    __syncthreads();

    // ---- per-row ranking: thread pair (2r, 2r+1) scans row r (64 cols each) ----
    {
        int r2 = tid >> 1;     // row 0..127
        int hf = tid & 1;      // half 0..1
        unsigned int v[8];
        #pragma unroll
        for (int s = 0; s < 8; ++s) v[s] = 0u;

        #pragma unroll
        for (int t8 = 0; t8 < 8; ++t8) {
            int slot = hf * 8 + t8;
            short8 x8 = *(const short8*)(smem + r2 * 136 + ((slot ^ (r2 & 7)) << 3));
            int gc0 = (int)col0 + slot * 8;
            #pragma unroll
            for (int jj = 0; jj < 8; ++jj) {
                unsigned int b = (unsigned short)x8[jj];
                unsigned int sr = (unsigned)((int)(b << 16) >> 31);
                unsigned int mono = b ^ ((sr >> 17) | 0x8000u);
                unsigned int keyv = (mono << 16) | (unsigned)(4095 - (gc0 + jj));
                if (keyv > v[7]) {
                    unsigned int x = keyv;
                    #pragma unroll
                    for (int s = 0; s < 8; ++s) {
                        unsigned int hi = v[s] > x ? v[s] : x;
                        unsigned int lo = v[s] > x ? x : v[s];
                        v[s] = hi; x = lo;
                    }
                }
            }
        }
        // merge partner halves: top-8 of union (bitonic select), sets identical in both lanes
        unsigned int nv[8];
        #pragma unroll
        for (int s = 0; s < 8; ++s) {
            unsigned int pv = (unsigned)__shfl_xor((int)v[7 - s], 1);
            nv[s] = v[s] > pv ? v[s] : pv;
        }
        if (hf == 0) {
            unsigned int* dst = cand + ((long long)bx * ROWS + row0 + r2) * 8;
            uint4 a = make_uint4(nv[0], nv[1], nv[2], nv[3]);
            uint4 bq = make_uint4(nv[4], nv[5], nv[6], nv[7]);
            *(uint4*)dst = a;
            *(uint4*)(dst + 4) = bq;
        }
    }
}

// ---------------- K4: gather 256 cand keys -> top-16 -> fp64 refine -> top-8 + ALL outputs ----------------
__global__ __launch_bounds__(256) void k_final2(const unsigned int* __restrict__ cand,
                                                const float* __restrict__ qf,
                                                const float* __restrict__ key,
                                                const float* __restrict__ mem,
                                                const float* __restrict__ mlab,
                                                float* __restrict__ gate,
                                                float* __restrict__ memr,
                                                float* __restrict__ labr,
                                                float* __restrict__ attw) {
    int tid = threadIdx.x;
    int lane = tid & 63;
    long long row = (long long)blockIdx.x * 4 + (tid >> 6);

    // ---- each lane loads 4 keys: tile = lane>>1, half (lane&1)*4 ----
    int tl = lane >> 1, of = (lane & 1) * 4;
    uint4 kk = *(const uint4*)(cand + ((long long)tl * ROWS + row) * 8 + of);

    unsigned int v[4];
    #pragma unroll
    for (int s = 0; s < 4; ++s) v[s] = 0u;
    {
        unsigned int ins[4] = {kk.x, kk.y, kk.z, kk.w};
        #pragma unroll
        for (int i = 0; i < 4; ++i) {
            unsigned int x = ins[i];
            #pragma unroll
            for (int s = 0; s < 4; ++s) {
                unsigned int hi = v[s] > x ? v[s] : x;
                unsigned int lo = v[s] > x ? x : v[s];
                v[s] = hi; x = lo;
            }
        }
    }

    // ---- extract global top-16 via wave-max pops ----
    unsigned int sk[KC];
    #pragma unroll
    for (int k = 0; k < KC; ++k) {
        unsigned int bv = v[0];
        #pragma unroll
        for (int d = 1; d < 64; d <<= 1) {
            unsigned int ov = (unsigned)__shfl_xor((int)bv, d);
            bv = bv > ov ? bv : ov;
        }
        sk[k] = bv;
        bool won = (v[0] == bv);
        v[0] = won ? v[1] : v[0];
        v[1] = won ? v[2] : v[1];
        v[2] = won ? v[3] : v[2];
        v[3] = won ? 0u : v[3];
    }

    int civ[KC];
    #pragma unroll
    for (int s = 0; s < KC; ++s) civ[s] = 4095 - (int)(sk[s] & 0xFFFu);

    // ---- refine: candidate c = lane&15, slice g = lane>>4, fp64 dot ----
    int c = lane & 15, g = lane >> 4;
    int cidx = civ[0];
    #pragma unroll
    for (int s = 1; s < KC; ++s) cidx = (c == s) ? civ[s] : cidx;
    const float* qrow = qf + row * Dd;
    const float* krow = key + (long long)cidx * Dd;
    double dacc = 0.0;
    #pragma unroll
    for (int i = 0; i < 16; ++i) {
        float4 qv = *(const float4*)(qrow + g * 64 + i * 4);
        float4 kv = *(const float4*)(krow + g * 64 + i * 4);
        dacc = fma((double)qv.x, (double)kv.x, dacc);
        dacc = fma((double)qv.y, (double)kv.y, dacc);
        dacc = fma((double)qv.z, (double)kv.z, dacc);
        dacc = fma((double)qv.w, (double)kv.w, dacc);
    }
    dacc += __shfl_xor(dacc, 16);
    dacc += __shfl_xor(dacc, 32);
    float rvf = (float)dacc;

    float cv[KC];
    #pragma unroll
    for (int s = 0; s < KC; ++s) cv[s] = __shfl(rvf, s);

    // ---- all-pairs rank on (refined value desc, idx asc); selected = rank<8 ----
    unsigned int m32[KC];
    #pragma unroll
    for (int s = 0; s < KC; ++s) {
        unsigned int fb = __float_as_uint(cv[s]);
        m32[s] = fb ^ ((unsigned)((int)fb >> 31) | 0x80000000u);
    }
    bool sel[KC];
    #pragma unroll
    for (int s = 0; s < KC; ++s) {
        int r = 0;
        #pragma unroll
        for (int t = 0; t < KC; ++t) {
            if (t != s) {
                bool gt = (m32[t] > m32[s]) || (m32[t] == m32[s] && civ[t] < civ[s]);
                r += gt ? 1 : 0;
            }
        }
        sel[s] = (r < KSEL);
    }

    // ---- softmax over selected ----
    float mx = cv[0];
    #pragma unroll
    for (int s = 1; s < KC; ++s) mx = fmaxf(mx, cv[s]);
    float p[KC]; float z = 0.f;
    #pragma unroll
    for (int s = 0; s < KC; ++s) { p[s] = sel[s] ? expf(cv[s] - mx) : 0.f; z += p[s]; }
    float inv = 1.f / z;
    #pragma unroll
    for (int s = 0; s < KC; ++s) p[s] *= inv;

    // ---- mem_retrieved (reads mem rows; overwrites q row after full read) ----
    {
        float4 a = make_float4(0.f, 0.f, 0.f, 0.f);
        #pragma unroll
        for (int s = 0; s < KC; ++s) {
            if (sel[s]) {
                const float4 mv = *(const float4*)(mem + (long long)civ[s] * Dd + lane * 4);
                a.x = fmaf(p[s], mv.x, a.x); a.y = fmaf(p[s], mv.y, a.y);
                a.z = fmaf(p[s], mv.z, a.z); a.w = fmaf(p[s], mv.w, a.w);
            }
        }
        *(float4*)(memr + row * Dd + lane * 4) = a;
    }

    if (lane < Ee) {
        float s8 = 0.f;
        #pragma unroll
        for (int s = 0; s < KC; ++s)
            if (sel[s]) s8 = fmaf(p[s], mlab[(long long)civ[s] * Ee + lane], s8);
        gate[row * Ee + lane] = s8;
        labr[row * Ee + lane] = s8;
    }

    // ---- att_w row: NT zero-fill, barrier (drains stores), sparse insert ----
    float* awrow = attw + row * Mm;
    {
        f32x4 zz = (f32x4){0.f, 0.f, 0.f, 0.f};
        #pragma unroll
        for (int t = 0; t < 16; ++t)
            __builtin_nontemporal_store(zz, (f32x4*)(awrow + (t * 64 + lane) * 4));
    }
    __syncthreads();   // s_waitcnt vmcnt(0) + barrier: zero-stores ordered before inserts
    if (lane < KC) {
        float myp = p[0]; int myi = civ[0];
        #pragma unroll
        for (int s = 1; s < KC; ++s) {
            myp = (lane == s) ? p[s] : myp;
            myi = (lane == s) ? civ[s] : myi;
        }
        awrow[myi] = myp;   // unselected lanes write 0.0 at their own idx (true value is 0.0)
    }
}

extern "C" void kernel_launch(void* const* d_in, const int* in_sizes, int n_in,
                              void* d_out, int out_size, void* d_ws, size_t ws_size,
                              hipStream_t stream) {
    const float* prop = (const float*)d_in[0];
    const float* W    = (const float*)d_in[2];
    const float* bias = (const float*)d_in[3];
    const float* key  = (const float*)d_in[4];
    const float* mem  = (const float*)d_in[5];
    const float* wg   = (const float*)d_in[6];

    float* out  = (float*)d_out;
    float* gate = out + O_GATE;
    float* memr = out + O_MEMR;
    float* labr = out + O_LABR;
    float* mlab = out + O_MLAB;
    float* attw = out + O_ATTW;

    char* ws = (char*)d_ws;
    float*          WT   = (float*)(ws + WS_WT);
    unsigned short* kh   = (unsigned short*)(ws + WS_KH);
    unsigned int*   cand = (unsigned int*)(ws + WS_CAND);
    unsigned short* qh   = (unsigned short*)(ws + WS_QH);
    float*          qf   = memr;   // fp32 q in memr output region (dead before overwrite)

    k_prep<<<4368, 256, 0, stream>>>(W, WT, key, kh, mem, wg, mlab);
    k_q<<<ROWS / 16, 256, 0, stream>>>(prop, WT, bias, qf, qh);
    k_att<<<4096, 256, 0, stream>>>(qh, kh, cand);
    k_final2<<<ROWS / 4, 256, 0, stream>>>(cand, qf, key, mem, mlab, gate, memr, labr, attw);
}

// Round 11
// 247.959 us; speedup vs baseline: 2.3134x; 1.0630x over previous
//
#include <hip/hip_runtime.h>
#include <hip/hip_fp16.h>
#include <math.h>

#define Bb 8
#define Tt 4
#define Nn 2048
#define Dd 256
#define Mm 4096
#define Ee 8
#define ROWS (Bb*Nn)   // 16384
#define KSEL 8
#define KC 16          // ranking candidates

// output offsets (floats)
#define O_GATE 0LL
#define O_MEMR 131072LL
#define O_LABR 4325376LL
#define O_MLAB 4456448LL
#define O_ATTW 4489216LL

// ws layout (bytes)
#define WS_WT    0LL            // 256 KB fp32 WT
#define WS_KH    262144LL       // 2 MB f16 key
#define WS_CAND  16777216LL     // 16.8 MB u32 cand[32][16384][8]
#define WS_QH    150994944LL    // 8 MB f16 q

typedef float f32x4 __attribute__((ext_vector_type(4)));
typedef short short8 __attribute__((ext_vector_type(8)));
typedef _Float16 f16x8 __attribute__((ext_vector_type(8)));

__device__ __forceinline__ unsigned short f2h(float x) {
    __half h = __float2half(x);
    return *reinterpret_cast<unsigned short*>(&h);
}

__device__ __forceinline__ void gload_lds16(const void* g, void* l) {
    __builtin_amdgcn_global_load_lds(
        (const __attribute__((address_space(1))) unsigned int*)g,
        (__attribute__((address_space(3))) unsigned int*)l,
        16, 0, 0);
}

// ---------------- K0: prep (transpose W | key->f16 | mem_label) ----------------
// grid = 256 + 4096 + 16 = 4368 blocks
__global__ __launch_bounds__(256) void k_prep(const float* __restrict__ W, float* __restrict__ WT,
                                              const float* __restrict__ key, unsigned short* __restrict__ kh,
                                              const float* __restrict__ mem, const float* __restrict__ wg,
                                              float* __restrict__ mlab) {
    int b = blockIdx.x, tid = threadIdx.x;
    if (b < 256) {
        int i = b * 256 + tid;
        int r = i >> 8, c = i & 255;
        WT[c * 256 + r] = W[r * 256 + c];
    } else if (b < 256 + 4096) {
        int idx = (b - 256) * 256 + tid;     // covers all Mm*Dd = 1048576
        kh[idx] = f2h(key[idx]);
    } else {
        int m = (b - 4352) * 256 + tid;
        if (m < Mm) {
            float acc[Ee];
            #pragma unroll
            for (int e = 0; e < Ee; ++e) acc[e] = 0.f;
            const float* mr = mem + (long long)m * Dd;
            for (int d = 0; d < Dd; ++d) {
                float mv = mr[d];
                #pragma unroll
                for (int e = 0; e < Ee; ++e) acc[e] = fmaf(mv, wg[d * Ee + e], acc[e]);
            }
            float mx = acc[0];
            #pragma unroll
            for (int e = 1; e < Ee; ++e) mx = fmaxf(mx, acc[e]);
            float z = 0.f;
            #pragma unroll
            for (int e = 0; e < Ee; ++e) { acc[e] = expf(acc[e] - mx); z += acc[e]; }
            float inv = 1.f / z;
            #pragma unroll
            for (int e = 0; e < Ee; ++e) mlab[(long long)m * Ee + e] = acc[e] * inv;
        }
    }
}

// ---------------- K1: x = mean_T(prop); q = tanh(x @ W^T + b) -> f32 + f16 ----------------
__global__ __launch_bounds__(256) void k_q(const float* __restrict__ prop,
                                           const float* __restrict__ WT,
                                           const float* __restrict__ bias,
                                           float* __restrict__ qf,
                                           unsigned short* __restrict__ qh) {
    __shared__ float xs[16][256];
    int tid = threadIdx.x;
    int row0 = blockIdx.x * 16;
    // float4 prop loads: 4 rows per pass, thread -> (row = pass*4 + tid>>6, d4 = tid&63)
    #pragma unroll
    for (int pass = 0; pass < 4; ++pass) {
        int r = pass * 4 + (tid >> 6);
        int d4 = tid & 63;
        int row = row0 + r;
        int b = row >> 11;
        int n = row & 2047;
        const float4* p = (const float4*)(prop + ((long long)(b * Tt) * Nn + n) * Dd) + d4;
        float4 s = make_float4(0.f, 0.f, 0.f, 0.f);
        #pragma unroll
        for (int t = 0; t < Tt; ++t) {
            float4 v = p[(long long)t * Nn * Dd / 4];
            s.x += v.x; s.y += v.y; s.z += v.z; s.w += v.w;
        }
        xs[r][d4 * 4 + 0] = s.x * 0.25f;
        xs[r][d4 * 4 + 1] = s.y * 0.25f;
        xs[r][d4 * 4 + 2] = s.z * 0.25f;
        xs[r][d4 * 4 + 3] = s.w * 0.25f;
    }
    __syncthreads();
    float acc[16];
    #pragma unroll
    for (int r = 0; r < 16; ++r) acc[r] = 0.f;
    int c = tid;
    for (int d = 0; d < 256; ++d) {
        float wv = WT[d * 256 + c];
        #pragma unroll
        for (int r = 0; r < 16; ++r) acc[r] = fmaf(xs[r][d], wv, acc[r]);
    }
    float bv = bias[c];
    #pragma unroll
    for (int r = 0; r < 16; ++r) {
        float qv = tanhf(acc[r] + bv);
        long long o = (long long)(row0 + r) * Dd + c;
        qf[o] = qv;
        qh[o] = f2h(qv);
    }
}

// ---------------- K3: att tile = q @ key^T (fp16 MFMA) + top-8/row cand + attw tile zero ----------------
// 1D grid of 4096 blocks, bijective XCD swizzle (4096 % 8 == 0). No att matrix materialized.
__global__ __launch_bounds__(256) void k_att(const unsigned short* __restrict__ qh,
                                             const unsigned short* __restrict__ kh,
                                             unsigned int* __restrict__ cand,
                                             float* __restrict__ attw) {
    // staging uses [0, 8192); C-tile: 128 rows x stride 136 shorts, slot-XOR swizzled
    __shared__ __align__(16) unsigned short smem[17408];
    int bid = blockIdx.x;
    int swz = (bid & 7) * 512 + (bid >> 3);     // XCD-contiguous chunks
    int bx = swz & 31;                          // col tile 0..31
    int by = swz >> 5;                          // row tile 0..127
    int tid = threadIdx.x;
    int lane = tid & 63, w = tid >> 6;
    int wr = w >> 1, wc = w & 1;
    long long row0 = (long long)by * 128;
    long long col0 = (long long)bx * 128;

    f32x4 acc[4][4];
    #pragma unroll
    for (int m = 0; m < 4; ++m)
        #pragma unroll
        for (int n = 0; n < 4; ++n) acc[m][n] = (f32x4){0.f, 0.f, 0.f, 0.f};

    int rr = lane >> 2;
    int sp = lane & 3;

    auto stage = [&](int k0) {
        #pragma unroll
        for (int t = 0; t < 2; ++t) {
            const unsigned short* src = t ? kh : qh;
            long long b0 = t ? col0 : row0;
            #pragma unroll
            for (int i = 0; i < 2; ++i) {
                int r = w * 32 + i * 16 + rr;
                int sl = sp ^ ((r >> 1) & 3);
                const unsigned short* g = src + (b0 + r) * 256 + k0 * 32 + sl * 8;
                unsigned short* l = smem + t * 4096 + (w * 32 + i * 16) * 32;
                gload_lds16(g, l);
            }
        }
    };

    stage(0);
    for (int k0 = 0; k0 < 8; ++k0) {
        __syncthreads();
        int lr = lane & 15, j = lane >> 4;
        f16x8 ah[4], bh[4];
        #pragma unroll
        for (int m = 0; m < 4; ++m) {
            int r = wr * 64 + m * 16 + lr;
            int off = r * 32 + ((j ^ ((r >> 1) & 3)) * 8);
            ah[m] = *(const f16x8*)(smem + off);
        }
        #pragma unroll
        for (int n = 0; n < 4; ++n) {
            int r = wc * 64 + n * 16 + lr;
            int off = r * 32 + ((j ^ ((r >> 1) & 3)) * 8);
            bh[n] = *(const f16x8*)(smem + 4096 + off);
        }
        #pragma unroll
        for (int m = 0; m < 4; ++m)
            #pragma unroll
            for (int n = 0; n < 4; ++n)
                acc[m][n] = __builtin_amdgcn_mfma_f32_16x16x32_f16(ah[m], bh[n], acc[m][n], 0, 0, 0);
        if (k0 < 7) { __syncthreads(); stage(k0 + 1); }
    }

    // ---- NT zero-fill of this block's 128x128 attw tile (overlaps with epilogue/ranking) ----
    {
        f32x4 zz = (f32x4){0.f, 0.f, 0.f, 0.f};
        #pragma unroll
        for (int i = 0; i < 16; ++i) {
            int s = i * 256 + tid;              // f32x4 slot 0..4095
            int r = s >> 5, c4 = s & 31;        // lanes 0-31 cover one row (512B contiguous)
            __builtin_nontemporal_store(zz, (f32x4*)(attw + (row0 + r) * Mm + col0 + c4 * 4));
        }
    }

    // ---- C fragments -> LDS f16 (stride 136, slot-XOR swizzle on 8-short slots) ----
    __syncthreads();   // all waves done reading staging LDS
    {
        int lr = lane & 15, j = lane >> 4;
        #pragma unroll
        for (int m = 0; m < 4; ++m)
            #pragma unroll
            for (int n = 0; n < 4; ++n) {
                int c = wc * 64 + n * 16 + lr;
                #pragma unroll
                for (int reg = 0; reg < 4; ++reg) {
                    int r = wr * 64 + m * 16 + j * 4 + reg;
                    int pc = (((c >> 3) ^ (r & 7)) << 3) | (c & 7);
                    smem[r * 136 + pc] = f2h(acc[m][n][reg]);
                }
            }
    }
    __syncthreads();

    // ---- per-row ranking: thread pair (2r, 2r+1) scans row r (64 cols each) ----
    {
        int r2 = tid >> 1;     // row 0..127
        int hf = tid & 1;      // half 0..1
        unsigned int v[8];
        #pragma unroll
        for (int s = 0; s < 8; ++s) v[s] = 0u;

        #pragma unroll
        for (int t8 = 0; t8 < 8; ++t8) {
            int slot = hf * 8 + t8;
            short8 x8 = *(const short8*)(smem + r2 * 136 + ((slot ^ (r2 & 7)) << 3));
            int gc0 = (int)col0 + slot * 8;
            #pragma unroll
            for (int jj = 0; jj < 8; ++jj) {
                unsigned int b = (unsigned short)x8[jj];
                unsigned int sr = (unsigned)((int)(b << 16) >> 31);
                unsigned int mono = b ^ ((sr >> 17) | 0x8000u);
                unsigned int keyv = (mono << 16) | (unsigned)(4095 - (gc0 + jj));
                if (keyv > v[7]) {
                    unsigned int x = keyv;
                    #pragma unroll
                    for (int s = 0; s < 8; ++s) {
                        unsigned int hi = v[s] > x ? v[s] : x;
                        unsigned int lo = v[s] > x ? x : v[s];
                        v[s] = hi; x = lo;
                    }
                }
            }
        }
        // merge partner halves: top-8 of union (bitonic select), sets identical in both lanes
        unsigned int nv[8];
        #pragma unroll
        for (int s = 0; s < 8; ++s) {
            unsigned int pv = (unsigned)__shfl_xor((int)v[7 - s], 1);
            nv[s] = v[s] > pv ? v[s] : pv;
        }
        if (hf == 0) {
            unsigned int* dst = cand + ((long long)bx * ROWS + row0 + r2) * 8;
            uint4 a = make_uint4(nv[0], nv[1], nv[2], nv[3]);
            uint4 bq = make_uint4(nv[4], nv[5], nv[6], nv[7]);
            *(uint4*)dst = a;
            *(uint4*)(dst + 4) = bq;
        }
    }
}

// ---------------- K4: gather 256 cand keys -> top-16 -> fp64 refine -> top-8 + outputs ----------------
// attw rows were zeroed by k_att; only sparse inserts here.
__global__ __launch_bounds__(256) void k_final2(const unsigned int* __restrict__ cand,
                                                const float* __restrict__ qf,
                                                const float* __restrict__ key,
                                                const float* __restrict__ mem,
                                                const float* __restrict__ mlab,
                                                float* __restrict__ gate,
                                                float* __restrict__ memr,
                                                float* __restrict__ labr,
                                                float* __restrict__ attw) {
    int tid = threadIdx.x;
    int lane = tid & 63;
    long long row = (long long)blockIdx.x * 4 + (tid >> 6);

    // ---- each lane loads 4 keys: tile = lane>>1, half (lane&1)*4 ----
    int tl = lane >> 1, of = (lane & 1) * 4;
    uint4 kk = *(const uint4*)(cand + ((long long)tl * ROWS + row) * 8 + of);

    unsigned int v[4];
    #pragma unroll
    for (int s = 0; s < 4; ++s) v[s] = 0u;
    {
        unsigned int ins[4] = {kk.x, kk.y, kk.z, kk.w};
        #pragma unroll
        for (int i = 0; i < 4; ++i) {
            unsigned int x = ins[i];
            #pragma unroll
            for (int s = 0; s < 4; ++s) {
                unsigned int hi = v[s] > x ? v[s] : x;
                unsigned int lo = v[s] > x ? x : v[s];
                v[s] = hi; x = lo;
            }
        }
    }

    // ---- extract global top-16 via wave-max pops ----
    unsigned int sk[KC];
    #pragma unroll
    for (int k = 0; k < KC; ++k) {
        unsigned int bv = v[0];
        #pragma unroll
        for (int d = 1; d < 64; d <<= 1) {
            unsigned int ov = (unsigned)__shfl_xor((int)bv, d);
            bv = bv > ov ? bv : ov;
        }
        sk[k] = bv;
        bool won = (v[0] == bv);
        v[0] = won ? v[1] : v[0];
        v[1] = won ? v[2] : v[1];
        v[2] = won ? v[3] : v[2];
        v[3] = won ? 0u : v[3];
    }

    int civ[KC];
    #pragma unroll
    for (int s = 0; s < KC; ++s) civ[s] = 4095 - (int)(sk[s] & 0xFFFu);

    // ---- refine: candidate c = lane&15, slice g = lane>>4, fp64 dot ----
    int c = lane & 15, g = lane >> 4;
    int cidx = civ[0];
    #pragma unroll
    for (int s = 1; s < KC; ++s) cidx = (c == s) ? civ[s] : cidx;
    const float* qrow = qf + row * Dd;
    const float* krow = key + (long long)cidx * Dd;
    double dacc = 0.0;
    #pragma unroll
    for (int i = 0; i < 16; ++i) {
        float4 qv = *(const float4*)(qrow + g * 64 + i * 4);
        float4 kv = *(const float4*)(krow + g * 64 + i * 4);
        dacc = fma((double)qv.x, (double)kv.x, dacc);
        dacc = fma((double)qv.y, (double)kv.y, dacc);
        dacc = fma((double)qv.z, (double)kv.z, dacc);
        dacc = fma((double)qv.w, (double)kv.w, dacc);
    }
    dacc += __shfl_xor(dacc, 16);
    dacc += __shfl_xor(dacc, 32);
    float rvf = (float)dacc;

    float cv[KC];
    #pragma unroll
    for (int s = 0; s < KC; ++s) cv[s] = __shfl(rvf, s);

    // ---- all-pairs rank on (refined value desc, idx asc); selected = rank<8 ----
    unsigned int m32[KC];
    #pragma unroll
    for (int s = 0; s < KC; ++s) {
        unsigned int fb = __float_as_uint(cv[s]);
        m32[s] = fb ^ ((unsigned)((int)fb >> 31) | 0x80000000u);
    }
    bool sel[KC];
    #pragma unroll
    for (int s = 0; s < KC; ++s) {
        int r = 0;
        #pragma unroll
        for (int t = 0; t < KC; ++t) {
            if (t != s) {
                bool gt = (m32[t] > m32[s]) || (m32[t] == m32[s] && civ[t] < civ[s]);
                r += gt ? 1 : 0;
            }
        }
        sel[s] = (r < KSEL);
    }

    // ---- softmax over selected ----
    float mx = cv[0];
    #pragma unroll
    for (int s = 1; s < KC; ++s) mx = fmaxf(mx, cv[s]);
    float p[KC]; float z = 0.f;
    #pragma unroll
    for (int s = 0; s < KC; ++s) { p[s] = sel[s] ? expf(cv[s] - mx) : 0.f; z += p[s]; }
    float inv = 1.f / z;
    #pragma unroll
    for (int s = 0; s < KC; ++s) p[s] *= inv;

    // ---- mem_retrieved (reads mem rows; overwrites q row after full read) ----
    {
        float4 a = make_float4(0.f, 0.f, 0.f, 0.f);
        #pragma unroll
        for (int s = 0; s < KC; ++s) {
            if (sel[s]) {
                const float4 mv = *(const float4*)(mem + (long long)civ[s] * Dd + lane * 4);
                a.x = fmaf(p[s], mv.x, a.x); a.y = fmaf(p[s], mv.y, a.y);
                a.z = fmaf(p[s], mv.z, a.z); a.w = fmaf(p[s], mv.w, a.w);
            }
        }
        *(float4*)(memr + row * Dd + lane * 4) = a;
    }

    if (lane < Ee) {
        float s8 = 0.f;
        #pragma unroll
        for (int s = 0; s < KC; ++s)
            if (sel[s]) s8 = fmaf(p[s], mlab[(long long)civ[s] * Ee + lane], s8);
        gate[row * Ee + lane] = s8;
        labr[row * Ee + lane] = s8;
    }

    // ---- sparse insert into pre-zeroed attw row ----
    if (lane < KC) {
        float myp = p[0]; int myi = civ[0];
        #pragma unroll
        for (int s = 1; s < KC; ++s) {
            myp = (lane == s) ? p[s] : myp;
            myi = (lane == s) ? civ[s] : myi;
        }
        attw[row * Mm + myi] = myp;   // unselected lanes write 0.0 (true value there is 0.0)
    }
}

extern "C" void kernel_launch(void* const* d_in, const int* in_sizes, int n_in,
                              void* d_out, int out_size, void* d_ws, size_t ws_size,
                              hipStream_t stream) {
    const float* prop = (const float*)d_in[0];
    const float* W    = (const float*)d_in[2];
    const float* bias = (const float*)d_in[3];
    const float* key  = (const float*)d_in[4];
    const float* mem  = (const float*)d_in[5];
    const float* wg   = (const float*)d_in[6];

    float* out  = (float*)d_out;
    float* gate = out + O_GATE;
    float* memr = out + O_MEMR;
    float* labr = out + O_LABR;
    float* mlab = out + O_MLAB;
    float* attw = out + O_ATTW;

    char* ws = (char*)d_ws;
    float*          WT   = (float*)(ws + WS_WT);
    unsigned short* kh   = (unsigned short*)(ws + WS_KH);
    unsigned int*   cand = (unsigned int*)(ws + WS_CAND);
    unsigned short* qh   = (unsigned short*)(ws + WS_QH);
    float*          qf   = memr;   // fp32 q in memr output region (dead before overwrite)

    k_prep<<<4368, 256, 0, stream>>>(W, WT, key, kh, mem, wg, mlab);
    k_q<<<ROWS / 16, 256, 0, stream>>>(prop, WT, bias, qf, qh);
    k_att<<<4096, 256, 0, stream>>>(qh, kh, cand, attw);
    k_final2<<<ROWS / 4, 256, 0, stream>>>(cand, qf, key, mem, mlab, gate, memr, labr, attw);
}